// Round 2
// baseline (511.372 us; speedup 1.0000x reference)
//
#include <hip/hip_runtime.h>

#define D_MODEL 1024
#define S_LEN   2048
#define BATCH   4
#define NH      16
#define DH      64
#define M_ROWS  (BATCH * S_LEN)   // 8192

typedef __attribute__((ext_vector_type(8))) short short8;
typedef __attribute__((ext_vector_type(4))) float floatx4;
typedef unsigned short ushort_t;
typedef __attribute__((ext_vector_type(4))) ushort_t ushortx4;

__device__ __forceinline__ float bf2f(ushort_t h) {
    union { unsigned u; float f; } v; v.u = ((unsigned)h) << 16; return v.f;
}
__device__ __forceinline__ ushort_t f2bf(float f) {
    union { float f; unsigned u; } v; v.f = f;
    unsigned r = v.u + 0x7FFFu + ((v.u >> 16) & 1u);
    return (ushort_t)(r >> 16);
}

// ---------------------------------------------------------------------------
// fp32 -> bf16 downcast of x, W_qkv, W_o into workspace. 4 elems / thread.
// ---------------------------------------------------------------------------
#define N0 (M_ROWS * D_MODEL)        // x:      8,388,608
#define N1 (3 * D_MODEL * D_MODEL)   // W_qkv:  3,145,728
#define N2 (D_MODEL * D_MODEL)       // W_o:    1,048,576
#define NQUADS ((N0 + N1 + N2) / 4)  // 3,145,728

__global__ __launch_bounds__(256)
void cvt_f32_bf16(const float* __restrict__ s0, const float* __restrict__ s1,
                  const float* __restrict__ s2, ushort_t* __restrict__ d0,
                  ushort_t* __restrict__ d1, ushort_t* __restrict__ d2)
{
    const int q = blockIdx.x * 256 + threadIdx.x;
    if (q >= NQUADS) return;
    const float* s; ushort_t* d; int e;
    if (q < N0 / 4)            { s = s0; d = d0; e = q * 4; }
    else if (q < (N0 + N1) / 4){ s = s1; d = d1; e = q * 4 - N0; }
    else                       { s = s2; d = d2; e = q * 4 - N0 - N1; }
    const float4 v = *(const float4*)&s[e];
    ushortx4 o;
    o[0] = f2bf(v.x); o[1] = f2bf(v.y); o[2] = f2bf(v.z); o[3] = f2bf(v.w);
    *(ushortx4*)&d[e] = o;
}

// ---------------------------------------------------------------------------
// NT GEMM: C[M,N] = A[M,K] * B[N,K]^T + bias[N]. A,B bf16; bias fp32;
// fp32 accum; output bf16 or fp32 (template). 128x128 tile, BK=32,
// 4 waves of 64x64 (4x4 mfma_f32_16x16x32_bf16).
// ---------------------------------------------------------------------------
template<bool F32OUT>
__global__ __launch_bounds__(256)
void gemm_bt_bias(const ushort_t* __restrict__ A, const ushort_t* __restrict__ B,
                  const float* __restrict__ bias, void* __restrict__ Cv,
                  int M, int N, int K)
{
    constexpr int BK = 32, PAD = 8;
    __shared__ ushort_t As[128][BK + PAD];   // 80B row stride -> 2-way bank alias (free)
    __shared__ ushort_t Bs[128][BK + PAD];

    const int tid  = threadIdx.x;
    const int lane = tid & 63;
    const int wave = tid >> 6;
    const int quad = lane >> 4;
    const int l16  = lane & 15;
    const int bm   = blockIdx.y * 128;
    const int bn   = blockIdx.x * 128;
    const int wm   = (wave & 1) * 64;
    const int wn   = (wave >> 1) * 64;

    floatx4 acc[4][4] = {};

    const int r0 = tid >> 2;         // 0..63
    const int c0 = (tid & 3) * 8;    // 0,8,16,24

    for (int k0 = 0; k0 < K; k0 += BK) {
        __syncthreads();
        *(short8*)&As[r0][c0]      = *(const short8*)&A[(size_t)(bm + r0)      * K + k0 + c0];
        *(short8*)&As[r0 + 64][c0] = *(const short8*)&A[(size_t)(bm + r0 + 64) * K + k0 + c0];
        *(short8*)&Bs[r0][c0]      = *(const short8*)&B[(size_t)(bn + r0)      * K + k0 + c0];
        *(short8*)&Bs[r0 + 64][c0] = *(const short8*)&B[(size_t)(bn + r0 + 64) * K + k0 + c0];
        __syncthreads();

        short8 af[4], bfr[4];
        #pragma unroll
        for (int i = 0; i < 4; i++) af[i]  = *(const short8*)&As[wm + i * 16 + l16][quad * 8];
        #pragma unroll
        for (int i = 0; i < 4; i++) bfr[i] = *(const short8*)&Bs[wn + i * 16 + l16][quad * 8];

        #pragma unroll
        for (int mi = 0; mi < 4; mi++)
            #pragma unroll
            for (int ni = 0; ni < 4; ni++)
                acc[mi][ni] = __builtin_amdgcn_mfma_f32_16x16x32_bf16(af[mi], bfr[ni], acc[mi][ni], 0, 0, 0);
    }

    // Epilogue: C/D layout col = lane&15, row = quad*4 + reg
    #pragma unroll
    for (int ni = 0; ni < 4; ni++) {
        const int col = bn + wn + ni * 16 + l16;
        const float bv = bias[col];
        #pragma unroll
        for (int mi = 0; mi < 4; mi++)
            #pragma unroll
            for (int r = 0; r < 4; r++) {
                const int row = bm + wm + mi * 16 + quad * 4 + r;
                const float val = acc[mi][ni][r] + bv;
                if (F32OUT) ((float*)Cv)[(size_t)row * N + col] = val;
                else        ((ushort_t*)Cv)[(size_t)row * N + col] = f2bf(val);
            }
    }
}

// ---------------------------------------------------------------------------
// Causal flash attention. qkv layout: [B, S, 3*D_MODEL] (Q | K | V per row).
// Block: one (b,h), 64 q rows; 4 waves x 16 q rows. Online softmax.
// out: [B, S, D_MODEL] bf16 (head-interleaved, ready for output projection).
// ---------------------------------------------------------------------------
#define BQ  64
#define BKV 64

__global__ __launch_bounds__(256)
void attn_causal(const ushort_t* __restrict__ qkv, ushort_t* __restrict__ out)
{
    constexpr int KP = 8;
    __shared__ ushort_t Ks[BKV][DH + KP];       // K tile  [key][dh]
    __shared__ ushort_t Vt[DH][BKV + KP];       // V tile transposed [dh][key]
    __shared__ ushort_t Ps[4][16][BKV + KP];    // per-wave P (C-layout -> A-layout)

    const int tid  = threadIdx.x;
    const int lane = tid & 63;
    const int wave = tid >> 6;
    const int quad = lane >> 4;
    const int l16  = lane & 15;

    const int qt = blockIdx.x;
    const int bh = blockIdx.y;
    const int b  = bh >> 4;
    const int h  = bh & 15;
    const int q0 = qt * BQ;

    const size_t rstride = 3 * D_MODEL;
    const size_t base = (size_t)b * S_LEN * rstride;

    // Q A-fragment straight from global: A[m=lane&15][k=quad*8+j]
    const int qrow = q0 + wave * 16 + l16;
    const ushort_t* qptr = qkv + base + (size_t)qrow * rstride + h * DH;
    const short8 qf0 = *(const short8*)(qptr + quad * 8);
    const short8 qf1 = *(const short8*)(qptr + 32 + quad * 8);

    float m_run[4], l_run[4];
    floatx4 o_acc[4] = {};
    #pragma unroll
    for (int r = 0; r < 4; r++) { m_run[r] = -1e30f; l_run[r] = 0.f; }

    const int ntiles = qt + 1;   // causal: keys up to q0+BQ
    for (int t = 0; t < ntiles; t++) {
        const int kb = t * BKV;
        __syncthreads();
        // stage K (direct) and V (transposed): 64x64 bf16 each
        #pragma unroll
        for (int it = 0; it < 2; it++) {
            const int id = tid + it * 256;
            const int r = id >> 3;           // key row 0..63
            const int c = (id & 7) * 8;      // dh 0..56
            const size_t row = base + (size_t)(kb + r) * rstride + h * DH + c;
            *(short8*)&Ks[r][c] = *(const short8*)&qkv[row + D_MODEL];
            const short8 v8 = *(const short8*)&qkv[row + 2 * D_MODEL];
            #pragma unroll
            for (int j = 0; j < 8; j++) Vt[c + j][r] = (ushort_t)v8[j];
        }
        __syncthreads();

        // S = Q K^T  (scores: row = q quad*4+reg, col = key ns*16+l16)
        floatx4 sc[4];
        #pragma unroll
        for (int ns = 0; ns < 4; ns++) {
            const short8 kf0 = *(const short8*)&Ks[ns * 16 + l16][quad * 8];
            const short8 kf1 = *(const short8*)&Ks[ns * 16 + l16][32 + quad * 8];
            floatx4 z = {};
            z = __builtin_amdgcn_mfma_f32_16x16x32_bf16(qf0, kf0, z, 0, 0, 0);
            z = __builtin_amdgcn_mfma_f32_16x16x32_bf16(qf1, kf1, z, 0, 0, 0);
            sc[ns] = z;
        }

        // scale + causal mask + row max (cols live across the 16 lanes of a quad)
        float mt[4];
        #pragma unroll
        for (int r = 0; r < 4; r++) {
            const int qi = q0 + wave * 16 + quad * 4 + r;
            float mx = -1e30f;
            #pragma unroll
            for (int ns = 0; ns < 4; ns++) {
                const int kj = kb + ns * 16 + l16;
                float v = sc[ns][r] * 0.125f;
                v = (kj <= qi) ? v : -1e30f;
                sc[ns][r] = v;
                mx = fmaxf(mx, v);
            }
            mt[r] = mx;
        }
        #pragma unroll
        for (int off = 1; off < 16; off <<= 1)
            #pragma unroll
            for (int r = 0; r < 4; r++)
                mt[r] = fmaxf(mt[r], __shfl_xor(mt[r], off, 64));

        float alpha[4], rs[4];
        #pragma unroll
        for (int r = 0; r < 4; r++) {
            const float mnew = fmaxf(m_run[r], mt[r]);
            alpha[r] = __expf(m_run[r] - mnew);
            m_run[r] = mnew;
            float s = 0.f;
            #pragma unroll
            for (int ns = 0; ns < 4; ns++) {
                const float p = __expf(sc[ns][r] - mnew);
                sc[ns][r] = p;
                s += p;
            }
            rs[r] = s;
        }
        #pragma unroll
        for (int off = 1; off < 16; off <<= 1)
            #pragma unroll
            for (int r = 0; r < 4; r++)
                rs[r] += __shfl_xor(rs[r], off, 64);
        #pragma unroll
        for (int r = 0; r < 4; r++) l_run[r] = l_run[r] * alpha[r] + rs[r];

        // P: C-layout -> LDS -> A-layout (per-wave region, same-wave RAW)
        #pragma unroll
        for (int ns = 0; ns < 4; ns++)
            #pragma unroll
            for (int r = 0; r < 4; r++)
                Ps[wave][quad * 4 + r][ns * 16 + l16] = f2bf(sc[ns][r]);

        #pragma unroll
        for (int d = 0; d < 4; d++)
            #pragma unroll
            for (int r = 0; r < 4; r++)
                o_acc[d][r] *= alpha[r];

        const short8 pf0 = *(const short8*)&Ps[wave][l16][quad * 8];
        const short8 pf1 = *(const short8*)&Ps[wave][l16][32 + quad * 8];
        #pragma unroll
        for (int d = 0; d < 4; d++) {
            const short8 vf0 = *(const short8*)&Vt[d * 16 + l16][quad * 8];
            const short8 vf1 = *(const short8*)&Vt[d * 16 + l16][32 + quad * 8];
            o_acc[d] = __builtin_amdgcn_mfma_f32_16x16x32_bf16(pf0, vf0, o_acc[d], 0, 0, 0);
            o_acc[d] = __builtin_amdgcn_mfma_f32_16x16x32_bf16(pf1, vf1, o_acc[d], 0, 0, 0);
        }
    }

    // out[b, qi, h*64 + dh] = o / l
    #pragma unroll
    for (int d = 0; d < 4; d++)
        #pragma unroll
        for (int r = 0; r < 4; r++) {
            const int qi = q0 + wave * 16 + quad * 4 + r;
            out[(size_t)(b * S_LEN + qi) * D_MODEL + h * DH + d * 16 + l16] =
                f2bf(o_acc[d][r] / l_run[r]);
        }
}

// ---------------------------------------------------------------------------
extern "C" void kernel_launch(void* const* d_in, const int* in_sizes, int n_in,
                              void* d_out, int out_size, void* d_ws, size_t ws_size,
                              hipStream_t stream)
{
    const float* x    = (const float*)d_in[0];   // [4,2048,1024] fp32
    const float* Wqkv = (const float*)d_in[1];   // [3072,1024]   fp32
    const float* bqkv = (const float*)d_in[2];   // [3072]        fp32
    const float* Wo   = (const float*)d_in[3];   // [1024,1024]   fp32
    const float* bo   = (const float*)d_in[4];   // [1024]        fp32
    float* out = (float*)d_out;                  // [4,2048,1024] fp32

    ushort_t* xb    = (ushort_t*)d_ws;                     // N0 bf16
    ushort_t* wqkvb = xb + N0;                             // N1
    ushort_t* wob   = wqkvb + N1;                          // N2
    ushort_t* qkv   = wob + N2;                            // 8192*3072
    ushort_t* att   = qkv + (size_t)M_ROWS * 3 * D_MODEL;  // 8192*1024

    dim3 blk(256);
    cvt_f32_bf16<<<dim3((NQUADS + 255) / 256), blk, 0, stream>>>(x, Wqkv, Wo, xb, wqkvb, wob);
    // QKV projection: M=8192, N=3072, K=1024 -> bf16
    gemm_bt_bias<false><<<dim3((3 * D_MODEL) / 128, M_ROWS / 128), blk, 0, stream>>>(
        xb, wqkvb, bqkv, qkv, M_ROWS, 3 * D_MODEL, D_MODEL);
    // causal attention (bf16 in/out)
    attn_causal<<<dim3(S_LEN / BQ, BATCH * NH), blk, 0, stream>>>(qkv, att);
    // output projection: M=8192, N=1024, K=1024 -> fp32 d_out
    gemm_bt_bias<true><<<dim3(D_MODEL / 128, M_ROWS / 128), blk, 0, stream>>>(
        att, wob, bo, out, M_ROWS, D_MODEL, D_MODEL);
}